// Round 12
// baseline (6648.610 us; speedup 1.0000x reference)
//
#include <hip/hip_runtime.h>

// Problem sizes (fixed by the reference)
constexpr int D_ = 1024, E_ = 2048, B_ = 16, T_ = 1024;
constexpr int NWGC = 128;             // compute WGs: 16 W1-rows, 8 W2/Wc/Wgx-rows each
constexpr int NWGT = 256;             // + 128 heater WGs (DVFS clock keep-alive)
constexpr int TPB = 512;

typedef short bf16x8 __attribute__((ext_vector_type(8)));
typedef float f32x4  __attribute__((ext_vector_type(4)));
typedef unsigned u32x4 __attribute__((ext_vector_type(4)));

constexpr unsigned POIS = 0xFFFFFFFFu;   // impossible as (finite bf16, finite bf16) pair
constexpr unsigned DONE = 0xD0D0D0D0u;

// ---- LDS byte offsets (identical to r8/r11) ----
constexpr int W1F   = 0;                 // W1 frags: 64 kc * 1024 B
constexpr int W2CF  = 65536;             // [W2;Wc] frags: 64 kc * 1024 B
constexpr int WGXF  = 131072;            // Wgx compact frags: 16 KB
constexpr int ZB    = 147456;            // 16 B zero block
constexpr int REDo  = 147472;            // 8 waves * 260 f32
constexpr int GREDo = REDo + 8320;       // 8 waves * 136 f32
constexpr int GPo   = GREDo + 4352;      // 128 f32 gate-x partial
constexpr int BIo   = GPo + 512;         // 8 f32 bias slice
constexpr int LDS_BYTES = BIo + 32;
static_assert(LDS_BYTES <= 163840, "LDS over 160KB");
constexpr int REDS = 260, GRS = 136;

// ---- device-coherent (IF$) helpers ----
__device__ __forceinline__ void stcg_u(unsigned* p, unsigned v) {
    __hip_atomic_store(p, v, __ATOMIC_RELAXED, __HIP_MEMORY_SCOPE_AGENT);
}
// uncached 16B load + full drain (retry path; issue+wait in ONE asm)
__device__ __forceinline__ u32x4 ld1(const unsigned* p) {
    u32x4 r;
    asm volatile("global_load_dwordx4 %0, %1, off sc0 sc1\n\t"
                 "s_waitcnt vmcnt(0)"
                 : "=&v"(r) : "v"(p) : "memory");
    return r;
}
// four pipelined uncached 16B loads, single wait (one IF$ RT)
__device__ __forceinline__ void ld4(const unsigned* p0, const unsigned* p1,
                                    const unsigned* p2, const unsigned* p3,
                                    u32x4& a, u32x4& b, u32x4& c, u32x4& d) {
    asm volatile("global_load_dwordx4 %0, %4, off sc0 sc1\n\t"
                 "global_load_dwordx4 %1, %5, off sc0 sc1\n\t"
                 "global_load_dwordx4 %2, %6, off sc0 sc1\n\t"
                 "global_load_dwordx4 %3, %7, off sc0 sc1\n\t"
                 "s_waitcnt vmcnt(0)"
                 : "=&v"(a), "=&v"(b), "=&v"(c), "=&v"(d)
                 : "v"(p0), "v"(p1), "v"(p2), "v"(p3) : "memory");
}
// eight pipelined uncached 16B loads, single wait (one IF$ RT)
__device__ __forceinline__ void ld8(const unsigned* p0, const unsigned* p1,
                                    const unsigned* p2, const unsigned* p3,
                                    const unsigned* p4, const unsigned* p5,
                                    const unsigned* p6, const unsigned* p7,
                                    u32x4& a, u32x4& b, u32x4& c, u32x4& d,
                                    u32x4& e, u32x4& f, u32x4& h, u32x4& i) {
    asm volatile("global_load_dwordx4 %0, %8,  off sc0 sc1\n\t"
                 "global_load_dwordx4 %1, %9,  off sc0 sc1\n\t"
                 "global_load_dwordx4 %2, %10, off sc0 sc1\n\t"
                 "global_load_dwordx4 %3, %11, off sc0 sc1\n\t"
                 "global_load_dwordx4 %4, %12, off sc0 sc1\n\t"
                 "global_load_dwordx4 %5, %13, off sc0 sc1\n\t"
                 "global_load_dwordx4 %6, %14, off sc0 sc1\n\t"
                 "global_load_dwordx4 %7, %15, off sc0 sc1\n\t"
                 "s_waitcnt vmcnt(0)"
                 : "=&v"(a), "=&v"(b), "=&v"(c), "=&v"(d),
                   "=&v"(e), "=&v"(f), "=&v"(h), "=&v"(i)
                 : "v"(p0), "v"(p1), "v"(p2), "v"(p3),
                   "v"(p4), "v"(p5), "v"(p6), "v"(p7) : "memory");
}
__device__ __forceinline__ bool bad4(u32x4 u) {
    return (u.x == POIS) || (u.y == POIS) || (u.z == POIS) || (u.w == POIS);
}

// ---- bf16 helpers ----
__device__ __forceinline__ unsigned f2bf(float f) {
    unsigned u; __builtin_memcpy(&u, &f, 4);
    u += 0x7fffu + ((u >> 16) & 1u);   // RNE
    return u >> 16;
}
__device__ __forceinline__ unsigned packbf(float lo, float hi) {
    return f2bf(lo) | (f2bf(hi) << 16);
}
__device__ __forceinline__ bf16x8 pack8(float4 a, float4 b) {
    union { unsigned short us[8]; bf16x8 v; } r;
    r.us[0] = (unsigned short)f2bf(a.x); r.us[1] = (unsigned short)f2bf(a.y);
    r.us[2] = (unsigned short)f2bf(a.z); r.us[3] = (unsigned short)f2bf(a.w);
    r.us[4] = (unsigned short)f2bf(b.x); r.us[5] = (unsigned short)f2bf(b.y);
    r.us[6] = (unsigned short)f2bf(b.z); r.us[7] = (unsigned short)f2bf(b.w);
    return r.v;
}
__device__ __forceinline__ bf16x8 fragu(u32x4 u) {
    union { u32x4 a; bf16x8 v; } r; r.a = u; return r.v;
}

__global__ void __launch_bounds__(TPB, 1)
elman12(const float* __restrict__ x, const float* __restrict__ h0,
        const float* __restrict__ W1, const float* __restrict__ W2g,
        const float* __restrict__ Wgx, const float* __restrict__ Wgh,
        const float* __restrict__ bias, float* __restrict__ out,
        unsigned* __restrict__ hxg  /* 3 slots x [128][16][4] u32 */,
        unsigned* __restrict__ hidg /* 3 slots x [128][16][8] u32 */,
        unsigned* __restrict__ dflag)
{
    const int g = blockIdx.x, tid = threadIdx.x;

    // ================= heater WGs: keep the other 128 CUs (and DVFS) hot =========
    if (g >= NWGC) {
        float a = 1.0000001f + (float)(tid & 7) * 1e-7f, c = 0.9999999f;
        while (true) {
            #pragma unroll
            for (int it = 0; it < 128; ++it) {
                #pragma unroll
                for (int j = 0; j < 16; ++j) {
                    a = __builtin_fmaf(a, c, 1e-30f);
                    c = __builtin_fmaf(c, a, -1e-30f);
                }
            }
            asm volatile("" : "+v"(a), "+v"(c));   // keep the chain alive
            if (__hip_atomic_load(dflag, __ATOMIC_RELAXED, __HIP_MEMORY_SCOPE_AGENT) == DONE)
                break;
        }
        return;
    }

    extern __shared__ char sm[];
    float* REDF  = (float*)(sm + REDo);
    float* GREDF = (float*)(sm + GREDo);
    float* GPF   = (float*)(sm + GPo);
    float* BIF   = (float*)(sm + BIo);

    const int l = tid & 63, wv = tid >> 6;   // lane, wave
    const int c16 = l & 15, q = l >> 4;      // frag col(batch) / k-octet group

    // ================= prologue: build bf16 fragment LDS (identical to r8) =========
    {
        float* wght = (float*)(sm + W2CF);
        for (int i = tid; i < 8 * D_; i += TPB)
            wght[i] = Wgh[(size_t)(g * 8 + (i >> 10)) * D_ + (i & 1023)];
        if (tid < 8) BIF[tid] = bias[g * 8 + tid];
        if (tid == 0) *(float4*)(sm + ZB) = float4{0, 0, 0, 0};
        __syncthreads();

        float* wcf = (float*)(sm + W1F);
        {
            const int k4 = tid * 4;
            float4 acc[8];
            #pragma unroll
            for (int r = 0; r < 8; ++r) acc[r] = float4{0, 0, 0, 0};
            const float* wp = W2g + k4;
            for (int m = 0; m < D_; ++m) {
                float4 wvv = *(const float4*)wp; wp += E_;
                #pragma unroll
                for (int r = 0; r < 8; ++r) {
                    float gm = wght[r * D_ + m];
                    acc[r].x = fmaf(gm, wvv.x, acc[r].x);
                    acc[r].y = fmaf(gm, wvv.y, acc[r].y);
                    acc[r].z = fmaf(gm, wvv.z, acc[r].z);
                    acc[r].w = fmaf(gm, wvv.w, acc[r].w);
                }
            }
            __syncthreads();
            #pragma unroll
            for (int r = 0; r < 8; ++r) *(float4*)(wcf + r * E_ + k4) = acc[r];
        }
        __syncthreads();

        for (int i = tid; i < 4096; i += TPB) {   // [W2;Wc] frags
            int kc = i >> 6, l2 = i & 63, cc = l2 & 15, qq = l2 >> 4;
            int k = kc * 32 + qq * 8;
            float4 lo, hi;
            if (cc < 8) {
                const float* src = W2g + (size_t)(g * 8 + cc) * E_ + k;
                lo = *(const float4*)src; hi = *(const float4*)(src + 4);
            } else {
                const float* src = wcf + (cc - 8) * E_ + k;
                lo = *(const float4*)src; hi = *(const float4*)(src + 4);
            }
            *(bf16x8*)(sm + W2CF + i * 16) = pack8(lo, hi);
        }
        __syncthreads();

        for (int i = tid; i < 4096; i += TPB) {   // W1 frags
            int kc = i >> 6, l2 = i & 63, cc = l2 & 15, qq = l2 >> 4;
            const float* src = W1 + (size_t)(g * 16 + cc) * (2 * D_) + kc * 32 + qq * 8;
            *(bf16x8*)(sm + W1F + i * 16) =
                pack8(*(const float4*)src, *(const float4*)(src + 4));
        }
        for (int i = tid; i < 1024; i += TPB) {   // Wgx compact frags
            int kc = i >> 5, qq = (i >> 3) & 3, cc = i & 7;
            const float* src = Wgx + (size_t)(g * 8 + cc) * D_ + kc * 32 + qq * 8;
            *(bf16x8*)(sm + WGXF + kc * 512 + qq * 128 + cc * 16) =
                pack8(*(const float4*)src, *(const float4*)(src + 4));
        }
        __syncthreads();
    }

    const char* gz = sm + ZB;

    // ================= recurrence =================
    f32x4 accP1 = {0.f, 0.f, 0.f, 0.f}, accG = {0.f, 0.f, 0.f, 0.f};

    // x-work for t=0
    {
        #pragma unroll
        for (int i = 0; i < 4; ++i) {
            int kc = wv + i * 8;
            const float* xp = x + c16 * D_ + kc * 32 + q * 8;
            bf16x8 af = pack8(*(const float4*)xp, *(const float4*)(xp + 4));
            bf16x8 w1 = *(const bf16x8*)(sm + W1F + kc * 1024 + l * 16);
            accP1 = __builtin_amdgcn_mfma_f32_16x16x32_bf16(af, w1, accP1, 0, 0, 0);
            const char* ga = (c16 < 8) ? (sm + WGXF + kc * 512 + q * 128 + c16 * 16) : gz;
            bf16x8 wg = *(const bf16x8*)ga;
            accG = __builtin_amdgcn_mfma_f32_16x16x32_bf16(af, wg, accG, 0, 0, 0);
        }
    }

    int sW = 0, sP = 1, sR = 2;   // write / poison-next / read(h of t-1) slots

    for (int t = 0; t < T_; ++t) {
        // ================ A: P1 h-part (self-validating poll loads) ================
        if (t == 0) {
            #pragma unroll
            for (int i = 0; i < 4; ++i) {
                int kc = 32 + wv + i * 8;
                const float* hp = h0 + c16 * D_ + (kc - 32) * 32 + q * 8;
                bf16x8 af = pack8(*(const float4*)hp, *(const float4*)(hp + 4));
                bf16x8 w1 = *(const bf16x8*)(sm + W1F + kc * 1024 + l * 16);
                accP1 = __builtin_amdgcn_mfma_f32_16x16x32_bf16(af, w1, accP1, 0, 0, 0);
            }
        } else {
            const unsigned* hb = hxg + sR * 8192;
            const unsigned* p0 = hb + ((4 * wv +  0 + q) * 16 + c16) * 4;
            const unsigned* p1 = hb + ((4 * wv + 32 + q) * 16 + c16) * 4;
            const unsigned* p2 = hb + ((4 * wv + 64 + q) * 16 + c16) * 4;
            const unsigned* p3 = hb + ((4 * wv + 96 + q) * 16 + c16) * 4;
            u32x4 h0v, h1v, h2v, h3v;
            ld4(p0, p1, p2, p3, h0v, h1v, h2v, h3v);
            while (bad4(h0v)) h0v = ld1(p0);
            while (bad4(h1v)) h1v = ld1(p1);
            while (bad4(h2v)) h2v = ld1(p2);
            while (bad4(h3v)) h3v = ld1(p3);
            #pragma unroll
            for (int i = 0; i < 4; ++i) {
                u32x4 hv = (i == 0) ? h0v : (i == 1) ? h1v : (i == 2) ? h2v : h3v;
                bf16x8 w1 = *(const bf16x8*)(sm + W1F + (32 + wv + 8 * i) * 1024 + l * 16);
                accP1 = __builtin_amdgcn_mfma_f32_16x16x32_bf16(fragu(hv), w1, accP1, 0, 0, 0);
            }
        }

        // ================ B: reduce + tanh + publish hidden(t) ================
        #pragma unroll
        for (int i = 0; i < 4; ++i)
            REDF[wv * REDS + (q * 4 + i) * 16 + c16] = accP1[i];
        if (c16 < 8) {
            #pragma unroll
            for (int i = 0; i < 4; ++i)
                GREDF[wv * GRS + (q * 4 + i) * 8 + c16] = accG[i];
        }
        __syncthreads();   // sync1: all waves past A => slot sP's readers done grid-wide
        float tv = 0.f;
        if (wv < 4) {            // distributed hidden finalize: 1 output per lane
            const int e = wv * 64 + l;
            float s = 0;
            #pragma unroll
            for (int w = 0; w < 8; ++w) s += REDF[w * REDS + e];
            tv = tanhf(s);
        } else if (wv == 4 || wv == 5) {   // gate-x partial -> GPF (read in E)
            const int gt = (wv - 4) * 64 + l;
            float s = 0;
            #pragma unroll
            for (int w = 0; w < 8; ++w) s += GREDF[w * GRS + gt];
            GPF[gt] = s;
        } else if (wv == 6) {    // poison hidg slot sP; drain before sync2
            unsigned* z1 = hidg + sP * 16384 + g * 128 + l;
            stcg_u(z1, POIS); stcg_u(z1 + 64, POIS);
            asm volatile("s_waitcnt vmcnt(0)" ::: "memory");
        } else {                 // wv == 7: poison hxg slot sP; drain before sync2
            stcg_u(hxg + sP * 8192 + g * 64 + l, POIS);
            asm volatile("s_waitcnt vmcnt(0)" ::: "memory");
        }
        __syncthreads();   // sync2: poisons drained; REDF free for D; GPF ready
        if (wv < 4) {      // publish (barrier orders it after the poison drains)
            float nb = __shfl_down(tv, 1, 64);
            if (!(l & 1)) {
                const int e = wv * 64 + l;
                stcg_u(hidg + sW * 16384 + g * 128 + (e >> 1), packbf(tv, nb));
            }
        }

        // ================ C: x-work for t+1 (overlaps hidden propagation) ============
        f32x4 accP1n = {0.f, 0.f, 0.f, 0.f}, accGn = {0.f, 0.f, 0.f, 0.f};
        if (t + 1 < T_) {
            const float* xt = x + (size_t)(t + 1) * (B_ * D_);
            #pragma unroll
            for (int i = 0; i < 4; ++i) {
                int kc = wv + i * 8;
                const float* xp = xt + c16 * D_ + kc * 32 + q * 8;
                bf16x8 af = pack8(*(const float4*)xp, *(const float4*)(xp + 4));
                bf16x8 w1 = *(const bf16x8*)(sm + W1F + kc * 1024 + l * 16);
                accP1n = __builtin_amdgcn_mfma_f32_16x16x32_bf16(af, w1, accP1n, 0, 0, 0);
                const char* ga = (c16 < 8) ? (sm + WGXF + kc * 512 + q * 128 + c16 * 16) : gz;
                bf16x8 wg = *(const bf16x8*)ga;
                accGn = __builtin_amdgcn_mfma_f32_16x16x32_bf16(af, wg, accGn, 0, 0, 0);
            }
        }

        // ================ D: P2 — 8 granule loads in ONE asm (single IF$ RT) ========
        {
            const unsigned* hb2 = hidg + sW * 16384;
            const unsigned* q0 = hb2 + ((2 * wv +   0 + (q >> 1)) * 16 + c16) * 8 + (q & 1) * 4;
            const unsigned* q1 = hb2 + ((2 * wv +  16 + (q >> 1)) * 16 + c16) * 8 + (q & 1) * 4;
            const unsigned* q2 = hb2 + ((2 * wv +  32 + (q >> 1)) * 16 + c16) * 8 + (q & 1) * 4;
            const unsigned* q3 = hb2 + ((2 * wv +  48 + (q >> 1)) * 16 + c16) * 8 + (q & 1) * 4;
            const unsigned* q4 = hb2 + ((2 * wv +  64 + (q >> 1)) * 16 + c16) * 8 + (q & 1) * 4;
            const unsigned* q5 = hb2 + ((2 * wv +  80 + (q >> 1)) * 16 + c16) * 8 + (q & 1) * 4;
            const unsigned* q6 = hb2 + ((2 * wv +  96 + (q >> 1)) * 16 + c16) * 8 + (q & 1) * 4;
            const unsigned* q7 = hb2 + ((2 * wv + 112 + (q >> 1)) * 16 + c16) * 8 + (q & 1) * 4;
            u32x4 u0, u1, u2, u3, u4, u5, u6, u7;
            ld8(q0, q1, q2, q3, q4, q5, q6, q7, u0, u1, u2, u3, u4, u5, u6, u7);
            while (bad4(u0)) u0 = ld1(q0);
            while (bad4(u1)) u1 = ld1(q1);
            while (bad4(u2)) u2 = ld1(q2);
            while (bad4(u3)) u3 = ld1(q3);
            while (bad4(u4)) u4 = ld1(q4);
            while (bad4(u5)) u5 = ld1(q5);
            while (bad4(u6)) u6 = ld1(q6);
            while (bad4(u7)) u7 = ld1(q7);
            f32x4 acc2 = {0.f, 0.f, 0.f, 0.f};
            #pragma unroll
            for (int i = 0; i < 8; ++i) {
                u32x4 uv = (i == 0) ? u0 : (i == 1) ? u1 : (i == 2) ? u2 : (i == 3) ? u3
                         : (i == 4) ? u4 : (i == 5) ? u5 : (i == 6) ? u6 : u7;
                bf16x8 w2 = *(const bf16x8*)(sm + W2CF + (wv + 8 * i) * 1024 + l * 16);
                acc2 = __builtin_amdgcn_mfma_f32_16x16x32_bf16(fragu(uv), w2, acc2, 0, 0, 0);
            }
            #pragma unroll
            for (int i = 0; i < 4; ++i)
                REDF[wv * REDS + (q * 4 + i) * 16 + c16] = acc2[i];
        }

        // ================ E: finalize out, publish h(t) ================
        __syncthreads();   // sync3
        float4 s4 = {0.f, 0.f, 0.f, 0.f};
        if (wv == 0) {
            #pragma unroll
            for (int w = 0; w < 8; ++w) {
                float4 v = *(const float4*)(REDF + w * REDS + 4 * l);
                s4.x += v.x; s4.y += v.y; s4.z += v.z; s4.w += v.w;
            }
        }
        __syncthreads();   // sync4: REDF free for next-step P1
        if (wv == 0) {
            float4 u4v;
            u4v.x = __shfl(s4.x, l + 2, 64); u4v.y = __shfl(s4.y, l + 2, 64);
            u4v.z = __shfl(s4.z, l + 2, 64); u4v.w = __shfl(s4.w, l + 2, 64);
            if ((l & 3) < 2) {
                int b = l >> 2, r0 = 4 * (l & 3);
                float oo[4];
                #pragma unroll
                for (int j = 0; j < 4; ++j) {
                    float hn = (j == 0) ? s4.x : (j == 1) ? s4.y : (j == 2) ? s4.z : s4.w;
                    float uj = (j == 0) ? u4v.x : (j == 1) ? u4v.y : (j == 2) ? u4v.z : u4v.w;
                    float uv = uj + GPF[b * 8 + r0 + j] + BIF[r0 + j];
                    float sig = 1.0f / (1.0f + __expf(-uv));
                    oo[j] = hn * (uv * sig);
                }
                *(float4*)(out + (size_t)t * (B_ * D_) + b * D_ + g * 8 + r0) =
                    float4{oo[0], oo[1], oo[2], oo[3]};
                unsigned* hdst = hxg + sW * 8192 + (g * 16 + b) * 4 + (r0 >> 1);
                stcg_u(hdst,     packbf(oo[0], oo[1]));
                stcg_u(hdst + 1, packbf(oo[2], oo[3]));
                // no drain, no flag — data self-validates
            }
        }

        // rotate slots: next step writes sP, reads sW, poisons sR(old)
        int tmp = sR; sR = sW; sW = sP; sP = tmp;
        accP1 = accP1n; accG = accGn;
    }

    // signal heaters to exit (one writer; heaters poll relaxed)
    if (g == 0 && tid == 0) stcg_u(dflag, DONE);
}

extern "C" void kernel_launch(void* const* d_in, const int* in_sizes, int n_in,
                              void* d_out, int out_size, void* d_ws, size_t ws_size,
                              hipStream_t stream) {
    const float* x    = (const float*)d_in[0];
    const float* h0   = (const float*)d_in[1];
    const float* W1   = (const float*)d_in[2];
    const float* W2   = (const float*)d_in[3];
    const float* Wgx  = (const float*)d_in[4];
    const float* Wgh  = (const float*)d_in[5];
    const float* bias = (const float*)d_in[6];
    float* out = (float*)d_out;

    unsigned* hidg  = (unsigned*)d_ws;          // 3 slots x 64KB = 192 KB
    unsigned* hxg   = hidg + 3 * 16384;         // 3 slots x 32KB = 96 KB
    unsigned* dflag = hxg + 3 * 8192;           // done flag (after ring buffers)

    // Ring slots + flag start as 0xFF (POISON / not-DONE); runs every replay.
    hipMemsetAsync(d_ws, 0xFF, 294912 + 64, stream);

    hipFuncSetAttribute((const void*)elman12,
                        hipFuncAttributeMaxDynamicSharedMemorySize, LDS_BYTES);

    void* args[] = {(void*)&x, (void*)&h0, (void*)&W1, (void*)&W2,
                    (void*)&Wgx, (void*)&Wgh, (void*)&bias, (void*)&out,
                    (void*)&hxg, (void*)&hidg, (void*)&dflag};
    hipLaunchCooperativeKernel((const void*)elman12,
                               dim3(NWGT), dim3(TPB), args,
                               (unsigned)LDS_BYTES, stream);
}

// Round 13
// 6198.619 us; speedup vs baseline: 1.0726x; 1.0726x over previous
//
#include <hip/hip_runtime.h>

// Problem sizes (fixed by the reference)
constexpr int D_ = 1024, E_ = 2048, B_ = 16, T_ = 1024;
constexpr int NWG = 128, TPB = 512;   // 128 WGs: 16 W1-rows, 8 W2/Wc/Wgx-rows each

typedef short bf16x8 __attribute__((ext_vector_type(8)));
typedef float f32x4  __attribute__((ext_vector_type(4)));
typedef unsigned u32x4 __attribute__((ext_vector_type(4)));

constexpr unsigned POIS = 0xFFFFFFFFu;   // impossible as (finite bf16, finite bf16) pair

// ---- LDS byte offsets (identical to r8/r11) ----
constexpr int W1F   = 0;                 // W1 frags: 64 kc * 1024 B
constexpr int W2CF  = 65536;             // [W2;Wc] frags: 64 kc * 1024 B
constexpr int WGXF  = 131072;            // Wgx compact frags: 16 KB
constexpr int ZB    = 147456;            // 16 B zero block
constexpr int REDo  = 147472;            // 8 waves * 260 f32
constexpr int GREDo = REDo + 8320;       // 8 waves * 136 f32
constexpr int GPo   = GREDo + 4352;      // 128 f32 gate-x partial
constexpr int BIo   = GPo + 512;         // 8 f32 bias slice
constexpr int LDS_BYTES = BIo + 32;
static_assert(LDS_BYTES <= 163840, "LDS over 160KB");
constexpr int REDS = 260, GRS = 136;

// ---- device-coherent (IF$) helpers ----
__device__ __forceinline__ void stcg_u(unsigned* p, unsigned v) {
    __hip_atomic_store(p, v, __ATOMIC_RELAXED, __HIP_MEMORY_SCOPE_AGENT);
}
// four pipelined uncached 16B loads, single wait (one IF$ RT; exec-masked —
// in a divergent retry loop only still-stale lanes re-issue)
__device__ __forceinline__ void ld4(const unsigned* p0, const unsigned* p1,
                                    const unsigned* p2, const unsigned* p3,
                                    u32x4& a, u32x4& b, u32x4& c, u32x4& d) {
    asm volatile("global_load_dwordx4 %0, %4, off sc0 sc1\n\t"
                 "global_load_dwordx4 %1, %5, off sc0 sc1\n\t"
                 "global_load_dwordx4 %2, %6, off sc0 sc1\n\t"
                 "global_load_dwordx4 %3, %7, off sc0 sc1\n\t"
                 "s_waitcnt vmcnt(0)"
                 : "=&v"(a), "=&v"(b), "=&v"(c), "=&v"(d)
                 : "v"(p0), "v"(p1), "v"(p2), "v"(p3) : "memory");
}
// eight pipelined uncached 16B loads, single wait (one IF$ RT)
__device__ __forceinline__ void ld8(const unsigned* p0, const unsigned* p1,
                                    const unsigned* p2, const unsigned* p3,
                                    const unsigned* p4, const unsigned* p5,
                                    const unsigned* p6, const unsigned* p7,
                                    u32x4& a, u32x4& b, u32x4& c, u32x4& d,
                                    u32x4& e, u32x4& f, u32x4& h, u32x4& i) {
    asm volatile("global_load_dwordx4 %0, %8,  off sc0 sc1\n\t"
                 "global_load_dwordx4 %1, %9,  off sc0 sc1\n\t"
                 "global_load_dwordx4 %2, %10, off sc0 sc1\n\t"
                 "global_load_dwordx4 %3, %11, off sc0 sc1\n\t"
                 "global_load_dwordx4 %4, %12, off sc0 sc1\n\t"
                 "global_load_dwordx4 %5, %13, off sc0 sc1\n\t"
                 "global_load_dwordx4 %6, %14, off sc0 sc1\n\t"
                 "global_load_dwordx4 %7, %15, off sc0 sc1\n\t"
                 "s_waitcnt vmcnt(0)"
                 : "=&v"(a), "=&v"(b), "=&v"(c), "=&v"(d),
                   "=&v"(e), "=&v"(f), "=&v"(h), "=&v"(i)
                 : "v"(p0), "v"(p1), "v"(p2), "v"(p3),
                   "v"(p4), "v"(p5), "v"(p6), "v"(p7) : "memory");
}
__device__ __forceinline__ bool bad4(u32x4 u) {
    return (u.x == POIS) || (u.y == POIS) || (u.z == POIS) || (u.w == POIS);
}

// ---- bf16 helpers ----
__device__ __forceinline__ unsigned f2bf(float f) {
    unsigned u; __builtin_memcpy(&u, &f, 4);
    u += 0x7fffu + ((u >> 16) & 1u);   // RNE
    return u >> 16;
}
__device__ __forceinline__ unsigned packbf(float lo, float hi) {
    return f2bf(lo) | (f2bf(hi) << 16);
}
__device__ __forceinline__ bf16x8 pack8(float4 a, float4 b) {
    union { unsigned short us[8]; bf16x8 v; } r;
    r.us[0] = (unsigned short)f2bf(a.x); r.us[1] = (unsigned short)f2bf(a.y);
    r.us[2] = (unsigned short)f2bf(a.z); r.us[3] = (unsigned short)f2bf(a.w);
    r.us[4] = (unsigned short)f2bf(b.x); r.us[5] = (unsigned short)f2bf(b.y);
    r.us[6] = (unsigned short)f2bf(b.z); r.us[7] = (unsigned short)f2bf(b.w);
    return r.v;
}
__device__ __forceinline__ bf16x8 fragu(u32x4 u) {
    union { u32x4 a; bf16x8 v; } r; r.a = u; return r.v;
}

__global__ void __launch_bounds__(TPB, 1)
elman13(const float* __restrict__ x, const float* __restrict__ h0,
        const float* __restrict__ W1, const float* __restrict__ W2g,
        const float* __restrict__ Wgx, const float* __restrict__ Wgh,
        const float* __restrict__ bias, float* __restrict__ out,
        unsigned* __restrict__ hxg  /* 3 slots x [128][16][4] u32 */,
        unsigned* __restrict__ hidg /* 3 slots x [128][16][8] u32 */)
{
    extern __shared__ char sm[];
    float* REDF  = (float*)(sm + REDo);
    float* GREDF = (float*)(sm + GREDo);
    float* GPF   = (float*)(sm + GPo);
    float* BIF   = (float*)(sm + BIo);

    const int g = blockIdx.x, tid = threadIdx.x;
    const int l = tid & 63, wv = tid >> 6;   // lane, wave
    const int c16 = l & 15, q = l >> 4;      // frag col(batch) / k-octet group

    // ================= prologue: build bf16 fragment LDS (identical to r8) =========
    {
        float* wght = (float*)(sm + W2CF);
        for (int i = tid; i < 8 * D_; i += TPB)
            wght[i] = Wgh[(size_t)(g * 8 + (i >> 10)) * D_ + (i & 1023)];
        if (tid < 8) BIF[tid] = bias[g * 8 + tid];
        if (tid == 0) *(float4*)(sm + ZB) = float4{0, 0, 0, 0};
        __syncthreads();

        float* wcf = (float*)(sm + W1F);
        {
            const int k4 = tid * 4;
            float4 acc[8];
            #pragma unroll
            for (int r = 0; r < 8; ++r) acc[r] = float4{0, 0, 0, 0};
            const float* wp = W2g + k4;
            for (int m = 0; m < D_; ++m) {
                float4 wvv = *(const float4*)wp; wp += E_;
                #pragma unroll
                for (int r = 0; r < 8; ++r) {
                    float gm = wght[r * D_ + m];
                    acc[r].x = fmaf(gm, wvv.x, acc[r].x);
                    acc[r].y = fmaf(gm, wvv.y, acc[r].y);
                    acc[r].z = fmaf(gm, wvv.z, acc[r].z);
                    acc[r].w = fmaf(gm, wvv.w, acc[r].w);
                }
            }
            __syncthreads();
            #pragma unroll
            for (int r = 0; r < 8; ++r) *(float4*)(wcf + r * E_ + k4) = acc[r];
        }
        __syncthreads();

        for (int i = tid; i < 4096; i += TPB) {   // [W2;Wc] frags
            int kc = i >> 6, l2 = i & 63, cc = l2 & 15, qq = l2 >> 4;
            int k = kc * 32 + qq * 8;
            float4 lo, hi;
            if (cc < 8) {
                const float* src = W2g + (size_t)(g * 8 + cc) * E_ + k;
                lo = *(const float4*)src; hi = *(const float4*)(src + 4);
            } else {
                const float* src = wcf + (cc - 8) * E_ + k;
                lo = *(const float4*)src; hi = *(const float4*)(src + 4);
            }
            *(bf16x8*)(sm + W2CF + i * 16) = pack8(lo, hi);
        }
        __syncthreads();

        for (int i = tid; i < 4096; i += TPB) {   // W1 frags
            int kc = i >> 6, l2 = i & 63, cc = l2 & 15, qq = l2 >> 4;
            const float* src = W1 + (size_t)(g * 16 + cc) * (2 * D_) + kc * 32 + qq * 8;
            *(bf16x8*)(sm + W1F + i * 16) =
                pack8(*(const float4*)src, *(const float4*)(src + 4));
        }
        for (int i = tid; i < 1024; i += TPB) {   // Wgx compact frags
            int kc = i >> 5, qq = (i >> 3) & 3, cc = i & 7;
            const float* src = Wgx + (size_t)(g * 8 + cc) * D_ + kc * 32 + qq * 8;
            *(bf16x8*)(sm + WGXF + kc * 512 + qq * 128 + cc * 16) =
                pack8(*(const float4*)src, *(const float4*)(src + 4));
        }
        __syncthreads();
    }

    const char* gz = sm + ZB;

    // ================= recurrence =================
    f32x4 accP1 = {0.f, 0.f, 0.f, 0.f}, accG = {0.f, 0.f, 0.f, 0.f};

    // x-work for t=0
    {
        #pragma unroll
        for (int i = 0; i < 4; ++i) {
            int kc = wv + i * 8;
            const float* xp = x + c16 * D_ + kc * 32 + q * 8;
            bf16x8 af = pack8(*(const float4*)xp, *(const float4*)(xp + 4));
            bf16x8 w1 = *(const bf16x8*)(sm + W1F + kc * 1024 + l * 16);
            accP1 = __builtin_amdgcn_mfma_f32_16x16x32_bf16(af, w1, accP1, 0, 0, 0);
            const char* ga = (c16 < 8) ? (sm + WGXF + kc * 512 + q * 128 + c16 * 16) : gz;
            bf16x8 wg = *(const bf16x8*)ga;
            accG = __builtin_amdgcn_mfma_f32_16x16x32_bf16(af, wg, accG, 0, 0, 0);
        }
    }

    int sW = 0, sP = 1, sR = 2;   // write / poison-next / read(h of t-1) slots

    for (int t = 0; t < T_; ++t) {
        // ================ A: P1 h-part (batched self-validating poll) ================
        if (t == 0) {
            #pragma unroll
            for (int i = 0; i < 4; ++i) {
                int kc = 32 + wv + i * 8;
                const float* hp = h0 + c16 * D_ + (kc - 32) * 32 + q * 8;
                bf16x8 af = pack8(*(const float4*)hp, *(const float4*)(hp + 4));
                bf16x8 w1 = *(const bf16x8*)(sm + W1F + kc * 1024 + l * 16);
                accP1 = __builtin_amdgcn_mfma_f32_16x16x32_bf16(af, w1, accP1, 0, 0, 0);
            }
        } else {
            const unsigned* hb = hxg + sR * 8192;
            const unsigned* p0 = hb + ((4 * wv +  0 + q) * 16 + c16) * 4;
            const unsigned* p1 = hb + ((4 * wv + 32 + q) * 16 + c16) * 4;
            const unsigned* p2 = hb + ((4 * wv + 64 + q) * 16 + c16) * 4;
            const unsigned* p3 = hb + ((4 * wv + 96 + q) * 16 + c16) * 4;
            u32x4 h0v, h1v, h2v, h3v;
            ld4(p0, p1, p2, p3, h0v, h1v, h2v, h3v);
            // batched retry: one RT per round refreshes ALL stale granules
            while (bad4(h0v) || bad4(h1v) || bad4(h2v) || bad4(h3v))
                ld4(p0, p1, p2, p3, h0v, h1v, h2v, h3v);
            #pragma unroll
            for (int i = 0; i < 4; ++i) {
                u32x4 hv = (i == 0) ? h0v : (i == 1) ? h1v : (i == 2) ? h2v : h3v;
                bf16x8 w1 = *(const bf16x8*)(sm + W1F + (32 + wv + 8 * i) * 1024 + l * 16);
                accP1 = __builtin_amdgcn_mfma_f32_16x16x32_bf16(fragu(hv), w1, accP1, 0, 0, 0);
            }
        }

        // ================ B: reduce + tanh + publish hidden(t) ================
        #pragma unroll
        for (int i = 0; i < 4; ++i)
            REDF[wv * REDS + (q * 4 + i) * 16 + c16] = accP1[i];
        if (c16 < 8) {
            #pragma unroll
            for (int i = 0; i < 4; ++i)
                GREDF[wv * GRS + (q * 4 + i) * 8 + c16] = accG[i];
        }
        __syncthreads();   // sync1: all waves past A => slot sP's readers done grid-wide
        float tv = 0.f;
        if (wv < 4) {            // distributed hidden finalize: 1 output per lane
            const int e = wv * 64 + l;
            float s = 0;
            #pragma unroll
            for (int w = 0; w < 8; ++w) s += REDF[w * REDS + e];
            tv = tanhf(s);
        } else if (wv == 4 || wv == 5) {   // gate-x partial -> GPF (read in E)
            const int gt = (wv - 4) * 64 + l;
            float s = 0;
            #pragma unroll
            for (int w = 0; w < 8; ++w) s += GREDF[w * GRS + gt];
            GPF[gt] = s;
        } else if (wv == 6) {    // poison hidg slot sP; drain before sync2
            unsigned* z1 = hidg + sP * 16384 + g * 128 + l;
            stcg_u(z1, POIS); stcg_u(z1 + 64, POIS);
            asm volatile("s_waitcnt vmcnt(0)" ::: "memory");
        } else {                 // wv == 7: poison hxg slot sP; drain before sync2
            stcg_u(hxg + sP * 8192 + g * 64 + l, POIS);
            asm volatile("s_waitcnt vmcnt(0)" ::: "memory");
        }
        __syncthreads();   // sync2: poisons drained; REDF free for D; GPF ready
        if (wv < 4) {      // publish (barrier orders it after the poison drains)
            float nb = __shfl_down(tv, 1, 64);
            if (!(l & 1)) {
                const int e = wv * 64 + l;
                stcg_u(hidg + sW * 16384 + g * 128 + (e >> 1), packbf(tv, nb));
            }
        }

        // ================ C: x-work for t+1 (overlaps hidden propagation) ============
        f32x4 accP1n = {0.f, 0.f, 0.f, 0.f}, accGn = {0.f, 0.f, 0.f, 0.f};
        if (t + 1 < T_) {
            const float* xt = x + (size_t)(t + 1) * (B_ * D_);
            #pragma unroll
            for (int i = 0; i < 4; ++i) {
                int kc = wv + i * 8;
                const float* xp = xt + c16 * D_ + kc * 32 + q * 8;
                bf16x8 af = pack8(*(const float4*)xp, *(const float4*)(xp + 4));
                bf16x8 w1 = *(const bf16x8*)(sm + W1F + kc * 1024 + l * 16);
                accP1n = __builtin_amdgcn_mfma_f32_16x16x32_bf16(af, w1, accP1n, 0, 0, 0);
                const char* ga = (c16 < 8) ? (sm + WGXF + kc * 512 + q * 128 + c16 * 16) : gz;
                bf16x8 wg = *(const bf16x8*)ga;
                accGn = __builtin_amdgcn_mfma_f32_16x16x32_bf16(af, wg, accGn, 0, 0, 0);
            }
        }

        // ================ D: P2 — batched loads + batched retry ================
        {
            const unsigned* hb2 = hidg + sW * 16384;
            const unsigned* q0 = hb2 + ((2 * wv +   0 + (q >> 1)) * 16 + c16) * 8 + (q & 1) * 4;
            const unsigned* q1 = hb2 + ((2 * wv +  16 + (q >> 1)) * 16 + c16) * 8 + (q & 1) * 4;
            const unsigned* q2 = hb2 + ((2 * wv +  32 + (q >> 1)) * 16 + c16) * 8 + (q & 1) * 4;
            const unsigned* q3 = hb2 + ((2 * wv +  48 + (q >> 1)) * 16 + c16) * 8 + (q & 1) * 4;
            const unsigned* q4 = hb2 + ((2 * wv +  64 + (q >> 1)) * 16 + c16) * 8 + (q & 1) * 4;
            const unsigned* q5 = hb2 + ((2 * wv +  80 + (q >> 1)) * 16 + c16) * 8 + (q & 1) * 4;
            const unsigned* q6 = hb2 + ((2 * wv +  96 + (q >> 1)) * 16 + c16) * 8 + (q & 1) * 4;
            const unsigned* q7 = hb2 + ((2 * wv + 112 + (q >> 1)) * 16 + c16) * 8 + (q & 1) * 4;
            u32x4 u0, u1, u2, u3, u4, u5, u6, u7;
            ld8(q0, q1, q2, q3, q4, q5, q6, q7, u0, u1, u2, u3, u4, u5, u6, u7);
            while (bad4(u0) || bad4(u1) || bad4(u2) || bad4(u3) ||
                   bad4(u4) || bad4(u5) || bad4(u6) || bad4(u7))
                ld8(q0, q1, q2, q3, q4, q5, q6, q7, u0, u1, u2, u3, u4, u5, u6, u7);
            f32x4 acc2 = {0.f, 0.f, 0.f, 0.f};
            #pragma unroll
            for (int i = 0; i < 8; ++i) {
                u32x4 uv = (i == 0) ? u0 : (i == 1) ? u1 : (i == 2) ? u2 : (i == 3) ? u3
                         : (i == 4) ? u4 : (i == 5) ? u5 : (i == 6) ? u6 : u7;
                bf16x8 w2 = *(const bf16x8*)(sm + W2CF + (wv + 8 * i) * 1024 + l * 16);
                acc2 = __builtin_amdgcn_mfma_f32_16x16x32_bf16(fragu(uv), w2, acc2, 0, 0, 0);
            }
            #pragma unroll
            for (int i = 0; i < 4; ++i)
                REDF[wv * REDS + (q * 4 + i) * 16 + c16] = acc2[i];
        }

        // ================ E: finalize out, publish h(t) — distributed ================
        __syncthreads();   // sync3
        float ov = 0.f;
        if (wv < 2) {      // 1 output per lane across waves 0-1 (e = b*8 + r)
            const int e = wv * 64 + l, b = e >> 3, r = e & 7;
            float hn = 0, uv = 0;
            #pragma unroll
            for (int w = 0; w < 8; ++w) {
                hn += REDF[w * REDS + b * 16 + r];
                uv += REDF[w * REDS + b * 16 + 8 + r];
            }
            uv += GPF[e] + BIF[r];
            float sig = 1.0f / (1.0f + __expf(-uv));
            ov = hn * (uv * sig);
            out[(size_t)t * (B_ * D_) + b * D_ + g * 8 + r] = ov;   // plain cached
        }
        __syncthreads();   // sync4: REDF free for next-step P1
        if (wv < 2) {      // publish carried h (bf16 pairs; lanes even-e)
            float nb = __shfl_down(ov, 1, 64);
            if (!(l & 1)) {
                const int e = wv * 64 + l, b = e >> 3;
                stcg_u(hxg + sW * 8192 + (g * 16 + b) * 4 + ((e & 7) >> 1),
                       packbf(ov, nb));
                // no drain, no flag — data self-validates
            }
        }

        // rotate slots: next step writes sP, reads sW, poisons sR(old)
        int tmp = sR; sR = sW; sW = sP; sP = tmp;
        accP1 = accP1n; accG = accGn;
    }
}

extern "C" void kernel_launch(void* const* d_in, const int* in_sizes, int n_in,
                              void* d_out, int out_size, void* d_ws, size_t ws_size,
                              hipStream_t stream) {
    const float* x    = (const float*)d_in[0];
    const float* h0   = (const float*)d_in[1];
    const float* W1   = (const float*)d_in[2];
    const float* W2   = (const float*)d_in[3];
    const float* Wgx  = (const float*)d_in[4];
    const float* Wgh  = (const float*)d_in[5];
    const float* bias = (const float*)d_in[6];
    float* out = (float*)d_out;

    unsigned* hidg = (unsigned*)d_ws;          // 3 slots x 64KB = 192 KB
    unsigned* hxg  = hidg + 3 * 16384;         // 3 slots x 32KB = 96 KB

    // All ring slots start as POISON (0xFF bytes); runs every launch/replay.
    hipMemsetAsync(d_ws, 0xFF, 294912, stream);

    hipFuncSetAttribute((const void*)elman13,
                        hipFuncAttributeMaxDynamicSharedMemorySize, LDS_BYTES);

    void* args[] = {(void*)&x, (void*)&h0, (void*)&W1, (void*)&W2,
                    (void*)&Wgx, (void*)&Wgh, (void*)&bias, (void*)&out,
                    (void*)&hxg, (void*)&hidg};
    hipLaunchCooperativeKernel((const void*)elman13,
                               dim3(NWG), dim3(TPB), args,
                               (unsigned)LDS_BYTES, stream);
}

// Round 14
// 5555.975 us; speedup vs baseline: 1.1967x; 1.1157x over previous
//
#include <hip/hip_runtime.h>

// Problem sizes (fixed by the reference)
constexpr int D_ = 1024, E_ = 2048, B_ = 16, T_ = 1024;
constexpr int NWG = 128, TPB = 512;   // 128 WGs: 16 W1-rows, 8 W2/Wc/Wgx-rows each

typedef short bf16x8 __attribute__((ext_vector_type(8)));
typedef float f32x4  __attribute__((ext_vector_type(4)));
typedef unsigned u32x4 __attribute__((ext_vector_type(4)));

constexpr unsigned POIS = 0xFFFFFFFFu;   // impossible as (finite bf16, finite bf16) pair

// ---- LDS byte offsets (identical to r8/r11/r13) ----
constexpr int W1F   = 0;                 // W1 frags: 64 kc * 1024 B
constexpr int W2CF  = 65536;             // [W2;Wc] frags: 64 kc * 1024 B
constexpr int WGXF  = 131072;            // Wgx compact frags: 16 KB
constexpr int ZB    = 147456;            // 16 B zero block
constexpr int REDo  = 147472;            // 8 waves * 260 f32
constexpr int GREDo = REDo + 8320;       // 8 waves * 136 f32
constexpr int GPo   = GREDo + 4352;      // 128 f32 gate-x partial
constexpr int BIo   = GPo + 512;         // 8 f32 bias slice
constexpr int LDS_BYTES = BIo + 32;
static_assert(LDS_BYTES <= 163840, "LDS over 160KB");
constexpr int REDS = 260, GRS = 136;

// ---- device-coherent (IF$) helpers ----
__device__ __forceinline__ void stcg_u(unsigned* p, unsigned v) {
    __hip_atomic_store(p, v, __ATOMIC_RELAXED, __HIP_MEMORY_SCOPE_AGENT);
}
// four pipelined uncached 16B loads, single wait (one IF$ RT)
__device__ __forceinline__ void ld4(const unsigned* p0, const unsigned* p1,
                                    const unsigned* p2, const unsigned* p3,
                                    u32x4& a, u32x4& b, u32x4& c, u32x4& d) {
    asm volatile("global_load_dwordx4 %0, %4, off sc0 sc1\n\t"
                 "global_load_dwordx4 %1, %5, off sc0 sc1\n\t"
                 "global_load_dwordx4 %2, %6, off sc0 sc1\n\t"
                 "global_load_dwordx4 %3, %7, off sc0 sc1\n\t"
                 "s_waitcnt vmcnt(0)"
                 : "=&v"(a), "=&v"(b), "=&v"(c), "=&v"(d)
                 : "v"(p0), "v"(p1), "v"(p2), "v"(p3) : "memory");
}
// eight pipelined uncached 16B loads, single wait (one IF$ RT)
__device__ __forceinline__ void ld8(const unsigned* p0, const unsigned* p1,
                                    const unsigned* p2, const unsigned* p3,
                                    const unsigned* p4, const unsigned* p5,
                                    const unsigned* p6, const unsigned* p7,
                                    u32x4& a, u32x4& b, u32x4& c, u32x4& d,
                                    u32x4& e, u32x4& f, u32x4& h, u32x4& i) {
    asm volatile("global_load_dwordx4 %0, %8,  off sc0 sc1\n\t"
                 "global_load_dwordx4 %1, %9,  off sc0 sc1\n\t"
                 "global_load_dwordx4 %2, %10, off sc0 sc1\n\t"
                 "global_load_dwordx4 %3, %11, off sc0 sc1\n\t"
                 "global_load_dwordx4 %4, %12, off sc0 sc1\n\t"
                 "global_load_dwordx4 %5, %13, off sc0 sc1\n\t"
                 "global_load_dwordx4 %6, %14, off sc0 sc1\n\t"
                 "global_load_dwordx4 %7, %15, off sc0 sc1\n\t"
                 "s_waitcnt vmcnt(0)"
                 : "=&v"(a), "=&v"(b), "=&v"(c), "=&v"(d),
                   "=&v"(e), "=&v"(f), "=&v"(h), "=&v"(i)
                 : "v"(p0), "v"(p1), "v"(p2), "v"(p3),
                   "v"(p4), "v"(p5), "v"(p6), "v"(p7) : "memory");
}
__device__ __forceinline__ bool bad4(u32x4 u) {
    return (u.x == POIS) || (u.y == POIS) || (u.z == POIS) || (u.w == POIS);
}

// ---- bf16 helpers ----
__device__ __forceinline__ unsigned f2bf(float f) {
    unsigned u; __builtin_memcpy(&u, &f, 4);
    u += 0x7fffu + ((u >> 16) & 1u);   // RNE
    return u >> 16;
}
__device__ __forceinline__ unsigned packbf(float lo, float hi) {
    return f2bf(lo) | (f2bf(hi) << 16);
}
__device__ __forceinline__ bf16x8 pack8(float4 a, float4 b) {
    union { unsigned short us[8]; bf16x8 v; } r;
    r.us[0] = (unsigned short)f2bf(a.x); r.us[1] = (unsigned short)f2bf(a.y);
    r.us[2] = (unsigned short)f2bf(a.z); r.us[3] = (unsigned short)f2bf(a.w);
    r.us[4] = (unsigned short)f2bf(b.x); r.us[5] = (unsigned short)f2bf(b.y);
    r.us[6] = (unsigned short)f2bf(b.z); r.us[7] = (unsigned short)f2bf(b.w);
    return r.v;
}
__device__ __forceinline__ bf16x8 fragu(u32x4 u) {
    union { u32x4 a; bf16x8 v; } r; r.a = u; return r.v;
}

__global__ void __launch_bounds__(TPB, 1)
elman14(const float* __restrict__ x, const float* __restrict__ h0,
        const float* __restrict__ W1, const float* __restrict__ W2g,
        const float* __restrict__ Wgx, const float* __restrict__ Wgh,
        const float* __restrict__ bias, float* __restrict__ out,
        unsigned* __restrict__ hxg  /* 3 slots x [128][16][4] u32 */,
        unsigned* __restrict__ hidg /* 3 slots x [128][16][8] u32 */)
{
    extern __shared__ char sm[];
    float* REDF  = (float*)(sm + REDo);
    float* GREDF = (float*)(sm + GREDo);
    float* GPF   = (float*)(sm + GPo);
    float* BIF   = (float*)(sm + BIo);

    const int g = blockIdx.x, tid = threadIdx.x;
    const int l = tid & 63, wv = tid >> 6;   // lane, wave
    const int c16 = l & 15, q = l >> 4;      // frag col(batch) / k-octet group

    // ================= prologue: build bf16 fragment LDS (identical to r8) =========
    {
        float* wght = (float*)(sm + W2CF);
        for (int i = tid; i < 8 * D_; i += TPB)
            wght[i] = Wgh[(size_t)(g * 8 + (i >> 10)) * D_ + (i & 1023)];
        if (tid < 8) BIF[tid] = bias[g * 8 + tid];
        if (tid == 0) *(float4*)(sm + ZB) = float4{0, 0, 0, 0};
        __syncthreads();

        float* wcf = (float*)(sm + W1F);
        {
            const int k4 = tid * 4;
            float4 acc[8];
            #pragma unroll
            for (int r = 0; r < 8; ++r) acc[r] = float4{0, 0, 0, 0};
            const float* wp = W2g + k4;
            for (int m = 0; m < D_; ++m) {
                float4 wvv = *(const float4*)wp; wp += E_;
                #pragma unroll
                for (int r = 0; r < 8; ++r) {
                    float gm = wght[r * D_ + m];
                    acc[r].x = fmaf(gm, wvv.x, acc[r].x);
                    acc[r].y = fmaf(gm, wvv.y, acc[r].y);
                    acc[r].z = fmaf(gm, wvv.z, acc[r].z);
                    acc[r].w = fmaf(gm, wvv.w, acc[r].w);
                }
            }
            __syncthreads();
            #pragma unroll
            for (int r = 0; r < 8; ++r) *(float4*)(wcf + r * E_ + k4) = acc[r];
        }
        __syncthreads();

        for (int i = tid; i < 4096; i += TPB) {   // [W2;Wc] frags
            int kc = i >> 6, l2 = i & 63, cc = l2 & 15, qq = l2 >> 4;
            int k = kc * 32 + qq * 8;
            float4 lo, hi;
            if (cc < 8) {
                const float* src = W2g + (size_t)(g * 8 + cc) * E_ + k;
                lo = *(const float4*)src; hi = *(const float4*)(src + 4);
            } else {
                const float* src = wcf + (cc - 8) * E_ + k;
                lo = *(const float4*)src; hi = *(const float4*)(src + 4);
            }
            *(bf16x8*)(sm + W2CF + i * 16) = pack8(lo, hi);
        }
        __syncthreads();

        for (int i = tid; i < 4096; i += TPB) {   // W1 frags
            int kc = i >> 6, l2 = i & 63, cc = l2 & 15, qq = l2 >> 4;
            const float* src = W1 + (size_t)(g * 16 + cc) * (2 * D_) + kc * 32 + qq * 8;
            *(bf16x8*)(sm + W1F + i * 16) =
                pack8(*(const float4*)src, *(const float4*)(src + 4));
        }
        for (int i = tid; i < 1024; i += TPB) {   // Wgx compact frags
            int kc = i >> 5, qq = (i >> 3) & 3, cc = i & 7;
            const float* src = Wgx + (size_t)(g * 8 + cc) * D_ + kc * 32 + qq * 8;
            *(bf16x8*)(sm + WGXF + kc * 512 + qq * 128 + cc * 16) =
                pack8(*(const float4*)src, *(const float4*)(src + 4));
        }
        __syncthreads();
    }

    const char* gz = sm + ZB;

    // ================= recurrence =================
    f32x4 accP1 = {0.f, 0.f, 0.f, 0.f}, accG = {0.f, 0.f, 0.f, 0.f};

    // x-work for t=0
    {
        #pragma unroll
        for (int i = 0; i < 4; ++i) {
            int kc = wv + i * 8;
            const float* xp = x + c16 * D_ + kc * 32 + q * 8;
            bf16x8 af = pack8(*(const float4*)xp, *(const float4*)(xp + 4));
            bf16x8 w1 = *(const bf16x8*)(sm + W1F + kc * 1024 + l * 16);
            accP1 = __builtin_amdgcn_mfma_f32_16x16x32_bf16(af, w1, accP1, 0, 0, 0);
            const char* ga = (c16 < 8) ? (sm + WGXF + kc * 512 + q * 128 + c16 * 16) : gz;
            bf16x8 wg = *(const bf16x8*)ga;
            accG = __builtin_amdgcn_mfma_f32_16x16x32_bf16(af, wg, accG, 0, 0, 0);
        }
    }

    int sW = 0, sP = 1, sR = 2;   // write / poison-next / read(h of t-1) slots

    for (int t = 0; t < T_; ++t) {
        // ================ A: P1 h-part (batched self-validating poll) ================
        if (t == 0) {
            #pragma unroll
            for (int i = 0; i < 4; ++i) {
                int kc = 32 + wv + i * 8;
                const float* hp = h0 + c16 * D_ + (kc - 32) * 32 + q * 8;
                bf16x8 af = pack8(*(const float4*)hp, *(const float4*)(hp + 4));
                bf16x8 w1 = *(const bf16x8*)(sm + W1F + kc * 1024 + l * 16);
                accP1 = __builtin_amdgcn_mfma_f32_16x16x32_bf16(af, w1, accP1, 0, 0, 0);
            }
        } else {
            const unsigned* hb = hxg + sR * 8192;
            const unsigned* p0 = hb + ((4 * wv +  0 + q) * 16 + c16) * 4;
            const unsigned* p1 = hb + ((4 * wv + 32 + q) * 16 + c16) * 4;
            const unsigned* p2 = hb + ((4 * wv + 64 + q) * 16 + c16) * 4;
            const unsigned* p3 = hb + ((4 * wv + 96 + q) * 16 + c16) * 4;
            u32x4 h0v, h1v, h2v, h3v;
            ld4(p0, p1, p2, p3, h0v, h1v, h2v, h3v);
            // batched retry: one RT per round refreshes ALL stale granules
            while (bad4(h0v) || bad4(h1v) || bad4(h2v) || bad4(h3v))
                ld4(p0, p1, p2, p3, h0v, h1v, h2v, h3v);
            #pragma unroll
            for (int i = 0; i < 4; ++i) {
                u32x4 hv = (i == 0) ? h0v : (i == 1) ? h1v : (i == 2) ? h2v : h3v;
                bf16x8 w1 = *(const bf16x8*)(sm + W1F + (32 + wv + 8 * i) * 1024 + l * 16);
                accP1 = __builtin_amdgcn_mfma_f32_16x16x32_bf16(fragu(hv), w1, accP1, 0, 0, 0);
            }
        }

        // ================ B: reduce + tanh + EARLY publish hidden(t) ================
        #pragma unroll
        for (int i = 0; i < 4; ++i)
            REDF[wv * REDS + (q * 4 + i) * 16 + c16] = accP1[i];
        if (c16 < 8) {
            #pragma unroll
            for (int i = 0; i < 4; ++i)
                GREDF[wv * GRS + (q * 4 + i) * 8 + c16] = accG[i];
        }
        __syncthreads();   // sync1: all waves past A => slot sP's readers done grid-wide
        if (wv < 4) {            // distributed finalize + IMMEDIATE publish
            const int e = wv * 64 + l;
            float s = 0;
            #pragma unroll
            for (int w = 0; w < 8; ++w) s += REDF[w * REDS + e];
            float tv = tanhf(s);
            float nb = __shfl_down(tv, 1, 64);
            if (!(l & 1))       // slot sW-block-g poisoned @t-1B, drained @t-1D => safe
                stcg_u(hidg + sW * 16384 + g * 128 + (e >> 1), packbf(tv, nb));
        } else if (wv == 4 || wv == 5) {   // gate-x partial -> GPF (read in E)
            const int gt = (wv - 4) * 64 + l;
            float s = 0;
            #pragma unroll
            for (int w = 0; w < 8; ++w) s += GREDF[w * GRS + gt];
            GPF[gt] = s;
        } else if (wv == 6) {    // poison hidg slot sP — NO drain (D's ld8 vmcnt(0)
            unsigned* z1 = hidg + sP * 16384 + g * 128 + l;   //  drains before sync3)
            stcg_u(z1, POIS); stcg_u(z1 + 64, POIS);
        } else {                 // wv == 7: poison hxg slot sP — no drain (same proof)
            stcg_u(hxg + sP * 8192 + g * 64 + l, POIS);
        }
        __syncthreads();   // sync2: REDF free for D; GPF ready for E

        // ================ C: x-work for t+1 (overlaps hidden propagation) ============
        f32x4 accP1n = {0.f, 0.f, 0.f, 0.f}, accGn = {0.f, 0.f, 0.f, 0.f};
        if (t + 1 < T_) {
            const float* xt = x + (size_t)(t + 1) * (B_ * D_);
            #pragma unroll
            for (int i = 0; i < 4; ++i) {
                int kc = wv + i * 8;
                const float* xp = xt + c16 * D_ + kc * 32 + q * 8;
                bf16x8 af = pack8(*(const float4*)xp, *(const float4*)(xp + 4));
                bf16x8 w1 = *(const bf16x8*)(sm + W1F + kc * 1024 + l * 16);
                accP1n = __builtin_amdgcn_mfma_f32_16x16x32_bf16(af, w1, accP1n, 0, 0, 0);
                const char* ga = (c16 < 8) ? (sm + WGXF + kc * 512 + q * 128 + c16 * 16) : gz;
                bf16x8 wg = *(const bf16x8*)ga;
                accGn = __builtin_amdgcn_mfma_f32_16x16x32_bf16(af, wg, accGn, 0, 0, 0);
            }
        }

        // ================ D: P2 — batched loads + batched retry ================
        {
            const unsigned* hb2 = hidg + sW * 16384;
            const unsigned* q0 = hb2 + ((2 * wv +   0 + (q >> 1)) * 16 + c16) * 8 + (q & 1) * 4;
            const unsigned* q1 = hb2 + ((2 * wv +  16 + (q >> 1)) * 16 + c16) * 8 + (q & 1) * 4;
            const unsigned* q2 = hb2 + ((2 * wv +  32 + (q >> 1)) * 16 + c16) * 8 + (q & 1) * 4;
            const unsigned* q3 = hb2 + ((2 * wv +  48 + (q >> 1)) * 16 + c16) * 8 + (q & 1) * 4;
            const unsigned* q4 = hb2 + ((2 * wv +  64 + (q >> 1)) * 16 + c16) * 8 + (q & 1) * 4;
            const unsigned* q5 = hb2 + ((2 * wv +  80 + (q >> 1)) * 16 + c16) * 8 + (q & 1) * 4;
            const unsigned* q6 = hb2 + ((2 * wv +  96 + (q >> 1)) * 16 + c16) * 8 + (q & 1) * 4;
            const unsigned* q7 = hb2 + ((2 * wv + 112 + (q >> 1)) * 16 + c16) * 8 + (q & 1) * 4;
            u32x4 u0, u1, u2, u3, u4, u5, u6, u7;
            ld8(q0, q1, q2, q3, q4, q5, q6, q7, u0, u1, u2, u3, u4, u5, u6, u7);
            while (bad4(u0) || bad4(u1) || bad4(u2) || bad4(u3) ||
                   bad4(u4) || bad4(u5) || bad4(u6) || bad4(u7))
                ld8(q0, q1, q2, q3, q4, q5, q6, q7, u0, u1, u2, u3, u4, u5, u6, u7);
            f32x4 acc2 = {0.f, 0.f, 0.f, 0.f};
            #pragma unroll
            for (int i = 0; i < 8; ++i) {
                u32x4 uv = (i == 0) ? u0 : (i == 1) ? u1 : (i == 2) ? u2 : (i == 3) ? u3
                         : (i == 4) ? u4 : (i == 5) ? u5 : (i == 6) ? u6 : u7;
                bf16x8 w2 = *(const bf16x8*)(sm + W2CF + (wv + 8 * i) * 1024 + l * 16);
                acc2 = __builtin_amdgcn_mfma_f32_16x16x32_bf16(fragu(uv), w2, acc2, 0, 0, 0);
            }
            #pragma unroll
            for (int i = 0; i < 4; ++i)
                REDF[wv * REDS + (q * 4 + i) * 16 + c16] = acc2[i];
        }

        // ================ E: finalize out, EARLY publish h(t); no sync4 ============
        __syncthreads();   // sync3: D's REDF writes visible
        if (wv < 2) {      // 1 output per lane across waves 0-1 (e = b*8 + r)
            const int e = wv * 64 + l, b = e >> 3, r = e & 7;
            float hn = 0, uv = 0;
            #pragma unroll
            for (int w = 0; w < 8; ++w) {
                hn += REDF[w * REDS + b * 16 + r];
                uv += REDF[w * REDS + b * 16 + 8 + r];
            }
            uv += GPF[e] + BIF[r];
            float sig = 1.0f / (1.0f + __expf(-uv));
            float ov = hn * (uv * sig);
            out[(size_t)t * (B_ * D_) + b * D_ + g * 8 + r] = ov;   // plain cached
            float nb = __shfl_down(ov, 1, 64);
            if (!(l & 1))       // publish immediately (slot poisoned t-1, drained t-1 D)
                stcg_u(hxg + sW * 8192 + (g * 16 + b) * 4 + ((e & 7) >> 1),
                       packbf(ov, nb));
        }
        // no sync4: E's REDF/GPF reads are ordered against B(t+1) writes by sync1(t+1);
        // A(t+1) pollers self-validate against in-flight publishes.

        // rotate slots: next step writes sP, reads sW, poisons sR(old)
        int tmp = sR; sR = sW; sW = sP; sP = tmp;
        accP1 = accP1n; accG = accGn;
    }
}

extern "C" void kernel_launch(void* const* d_in, const int* in_sizes, int n_in,
                              void* d_out, int out_size, void* d_ws, size_t ws_size,
                              hipStream_t stream) {
    const float* x    = (const float*)d_in[0];
    const float* h0   = (const float*)d_in[1];
    const float* W1   = (const float*)d_in[2];
    const float* W2   = (const float*)d_in[3];
    const float* Wgx  = (const float*)d_in[4];
    const float* Wgh  = (const float*)d_in[5];
    const float* bias = (const float*)d_in[6];
    float* out = (float*)d_out;

    unsigned* hidg = (unsigned*)d_ws;          // 3 slots x 64KB = 192 KB
    unsigned* hxg  = hidg + 3 * 16384;         // 3 slots x 32KB = 96 KB

    // All ring slots start as POISON (0xFF bytes); runs every launch/replay.
    hipMemsetAsync(d_ws, 0xFF, 294912, stream);

    hipFuncSetAttribute((const void*)elman14,
                        hipFuncAttributeMaxDynamicSharedMemorySize, LDS_BYTES);

    void* args[] = {(void*)&x, (void*)&h0, (void*)&W1, (void*)&W2,
                    (void*)&Wgx, (void*)&Wgh, (void*)&bias, (void*)&out,
                    (void*)&hxg, (void*)&hidg};
    hipLaunchCooperativeKernel((const void*)elman14,
                               dim3(NWG), dim3(TPB), args,
                               (unsigned)LDS_BYTES, stream);
}

// Round 15
// 5383.421 us; speedup vs baseline: 1.2350x; 1.0321x over previous
//
#include <hip/hip_runtime.h>

// Problem sizes (fixed by the reference)
constexpr int D_ = 1024, E_ = 2048, B_ = 16, T_ = 1024;
constexpr int NWG = 128, TPB = 512;   // 128 WGs: 16 W1-rows, 8 W2/Wc/Wgx-rows each

typedef short bf16x8 __attribute__((ext_vector_type(8)));
typedef float f32x4  __attribute__((ext_vector_type(4)));
typedef unsigned u32x4 __attribute__((ext_vector_type(4)));

constexpr unsigned POIS = 0xFFFFFFFFu;   // impossible as (finite bf16, finite bf16) pair

// ---- LDS byte offsets (identical to r8/r11/r13/r14) ----
constexpr int W1F   = 0;                 // W1 frags: 64 kc * 1024 B
constexpr int W2CF  = 65536;             // [W2;Wc] frags: 64 kc * 1024 B
constexpr int WGXF  = 131072;            // Wgx compact frags: 16 KB
constexpr int ZB    = 147456;            // 16 B zero block
constexpr int REDo  = 147472;            // 8 waves * 260 f32
constexpr int GREDo = REDo + 8320;       // 8 waves * 136 f32
constexpr int GPo   = GREDo + 4352;      // 128 f32 gate-x partial
constexpr int BIo   = GPo + 512;         // 8 f32 bias slice
constexpr int LDS_BYTES = BIo + 32;
static_assert(LDS_BYTES <= 163840, "LDS over 160KB");
constexpr int REDS = 260, GRS = 136;

// ---- device-coherent (IF$) helpers ----
__device__ __forceinline__ void stcg_u(unsigned* p, unsigned v) {
    __hip_atomic_store(p, v, __ATOMIC_RELAXED, __HIP_MEMORY_SCOPE_AGENT);
}
// four pipelined uncached 16B loads, single wait (one IF$ RT)
__device__ __forceinline__ void ld4(const unsigned* p0, const unsigned* p1,
                                    const unsigned* p2, const unsigned* p3,
                                    u32x4& a, u32x4& b, u32x4& c, u32x4& d) {
    asm volatile("global_load_dwordx4 %0, %4, off sc0 sc1\n\t"
                 "global_load_dwordx4 %1, %5, off sc0 sc1\n\t"
                 "global_load_dwordx4 %2, %6, off sc0 sc1\n\t"
                 "global_load_dwordx4 %3, %7, off sc0 sc1\n\t"
                 "s_waitcnt vmcnt(0)"
                 : "=&v"(a), "=&v"(b), "=&v"(c), "=&v"(d)
                 : "v"(p0), "v"(p1), "v"(p2), "v"(p3) : "memory");
}
// eight pipelined uncached 16B loads, single wait (one IF$ RT)
__device__ __forceinline__ void ld8(const unsigned* p0, const unsigned* p1,
                                    const unsigned* p2, const unsigned* p3,
                                    const unsigned* p4, const unsigned* p5,
                                    const unsigned* p6, const unsigned* p7,
                                    u32x4& a, u32x4& b, u32x4& c, u32x4& d,
                                    u32x4& e, u32x4& f, u32x4& h, u32x4& i) {
    asm volatile("global_load_dwordx4 %0, %8,  off sc0 sc1\n\t"
                 "global_load_dwordx4 %1, %9,  off sc0 sc1\n\t"
                 "global_load_dwordx4 %2, %10, off sc0 sc1\n\t"
                 "global_load_dwordx4 %3, %11, off sc0 sc1\n\t"
                 "global_load_dwordx4 %4, %12, off sc0 sc1\n\t"
                 "global_load_dwordx4 %5, %13, off sc0 sc1\n\t"
                 "global_load_dwordx4 %6, %14, off sc0 sc1\n\t"
                 "global_load_dwordx4 %7, %15, off sc0 sc1\n\t"
                 "s_waitcnt vmcnt(0)"
                 : "=&v"(a), "=&v"(b), "=&v"(c), "=&v"(d),
                   "=&v"(e), "=&v"(f), "=&v"(h), "=&v"(i)
                 : "v"(p0), "v"(p1), "v"(p2), "v"(p3),
                   "v"(p4), "v"(p5), "v"(p6), "v"(p7) : "memory");
}
__device__ __forceinline__ bool bad4(u32x4 u) {
    return (u.x == POIS) || (u.y == POIS) || (u.z == POIS) || (u.w == POIS);
}

// ---- bf16 helpers ----
__device__ __forceinline__ unsigned f2bf(float f) {
    unsigned u; __builtin_memcpy(&u, &f, 4);
    u += 0x7fffu + ((u >> 16) & 1u);   // RNE
    return u >> 16;
}
__device__ __forceinline__ unsigned packbf(float lo, float hi) {
    return f2bf(lo) | (f2bf(hi) << 16);
}
__device__ __forceinline__ bf16x8 pack8(float4 a, float4 b) {
    union { unsigned short us[8]; bf16x8 v; } r;
    r.us[0] = (unsigned short)f2bf(a.x); r.us[1] = (unsigned short)f2bf(a.y);
    r.us[2] = (unsigned short)f2bf(a.z); r.us[3] = (unsigned short)f2bf(a.w);
    r.us[4] = (unsigned short)f2bf(b.x); r.us[5] = (unsigned short)f2bf(b.y);
    r.us[6] = (unsigned short)f2bf(b.z); r.us[7] = (unsigned short)f2bf(b.w);
    return r.v;
}
__device__ __forceinline__ bf16x8 fragu(u32x4 u) {
    union { u32x4 a; bf16x8 v; } r; r.a = u; return r.v;
}

__global__ void __launch_bounds__(TPB, 1)
elman15(const float* __restrict__ x, const float* __restrict__ h0,
        const float* __restrict__ W1, const float* __restrict__ W2g,
        const float* __restrict__ Wgx, const float* __restrict__ Wgh,
        const float* __restrict__ bias, float* __restrict__ out,
        unsigned* __restrict__ hxg  /* 3 slots x [128][16][4] u32 */,
        unsigned* __restrict__ hidg /* 3 slots x [128][16][8] u32 */)
{
    extern __shared__ char sm[];
    float* REDF  = (float*)(sm + REDo);
    float* GREDF = (float*)(sm + GREDo);
    float* GPF   = (float*)(sm + GPo);
    float* BIF   = (float*)(sm + BIo);

    const int g = blockIdx.x, tid = threadIdx.x;
    const int l = tid & 63, wv = tid >> 6;   // lane, wave
    const int c16 = l & 15, q = l >> 4;      // frag col(batch) / k-octet group

    // ================= prologue: build bf16 fragment LDS (identical to r8) =========
    {
        float* wght = (float*)(sm + W2CF);
        for (int i = tid; i < 8 * D_; i += TPB)
            wght[i] = Wgh[(size_t)(g * 8 + (i >> 10)) * D_ + (i & 1023)];
        if (tid < 8) BIF[tid] = bias[g * 8 + tid];
        if (tid == 0) *(float4*)(sm + ZB) = float4{0, 0, 0, 0};
        __syncthreads();

        float* wcf = (float*)(sm + W1F);
        {
            const int k4 = tid * 4;
            float4 acc[8];
            #pragma unroll
            for (int r = 0; r < 8; ++r) acc[r] = float4{0, 0, 0, 0};
            const float* wp = W2g + k4;
            for (int m = 0; m < D_; ++m) {
                float4 wvv = *(const float4*)wp; wp += E_;
                #pragma unroll
                for (int r = 0; r < 8; ++r) {
                    float gm = wght[r * D_ + m];
                    acc[r].x = fmaf(gm, wvv.x, acc[r].x);
                    acc[r].y = fmaf(gm, wvv.y, acc[r].y);
                    acc[r].z = fmaf(gm, wvv.z, acc[r].z);
                    acc[r].w = fmaf(gm, wvv.w, acc[r].w);
                }
            }
            __syncthreads();
            #pragma unroll
            for (int r = 0; r < 8; ++r) *(float4*)(wcf + r * E_ + k4) = acc[r];
        }
        __syncthreads();

        for (int i = tid; i < 4096; i += TPB) {   // [W2;Wc] frags
            int kc = i >> 6, l2 = i & 63, cc = l2 & 15, qq = l2 >> 4;
            int k = kc * 32 + qq * 8;
            float4 lo, hi;
            if (cc < 8) {
                const float* src = W2g + (size_t)(g * 8 + cc) * E_ + k;
                lo = *(const float4*)src; hi = *(const float4*)(src + 4);
            } else {
                const float* src = wcf + (cc - 8) * E_ + k;
                lo = *(const float4*)src; hi = *(const float4*)(src + 4);
            }
            *(bf16x8*)(sm + W2CF + i * 16) = pack8(lo, hi);
        }
        __syncthreads();

        for (int i = tid; i < 4096; i += TPB) {   // W1 frags
            int kc = i >> 6, l2 = i & 63, cc = l2 & 15, qq = l2 >> 4;
            const float* src = W1 + (size_t)(g * 16 + cc) * (2 * D_) + kc * 32 + qq * 8;
            *(bf16x8*)(sm + W1F + i * 16) =
                pack8(*(const float4*)src, *(const float4*)(src + 4));
        }
        for (int i = tid; i < 1024; i += TPB) {   // Wgx compact frags
            int kc = i >> 5, qq = (i >> 3) & 3, cc = i & 7;
            const float* src = Wgx + (size_t)(g * 8 + cc) * D_ + kc * 32 + qq * 8;
            *(bf16x8*)(sm + WGXF + kc * 512 + qq * 128 + cc * 16) =
                pack8(*(const float4*)src, *(const float4*)(src + 4));
        }
        __syncthreads();
    }

    const char* gz = sm + ZB;

    // ================= recurrence =================
    f32x4 accP1 = {0.f, 0.f, 0.f, 0.f}, accG = {0.f, 0.f, 0.f, 0.f};

    // x-work for t=0
    {
        #pragma unroll
        for (int i = 0; i < 4; ++i) {
            int kc = wv + i * 8;
            const float* xp = x + c16 * D_ + kc * 32 + q * 8;
            bf16x8 af = pack8(*(const float4*)xp, *(const float4*)(xp + 4));
            bf16x8 w1 = *(const bf16x8*)(sm + W1F + kc * 1024 + l * 16);
            accP1 = __builtin_amdgcn_mfma_f32_16x16x32_bf16(af, w1, accP1, 0, 0, 0);
            const char* ga = (c16 < 8) ? (sm + WGXF + kc * 512 + q * 128 + c16 * 16) : gz;
            bf16x8 wg = *(const bf16x8*)ga;
            accG = __builtin_amdgcn_mfma_f32_16x16x32_bf16(af, wg, accG, 0, 0, 0);
        }
    }

    int sW = 0, sP = 1, sR = 2;   // write / poison-next / read(h of t-1) slots

    for (int t = 0; t < T_; ++t) {
        // ====== hoisted x(t+1) loads: plain compiler-visible loads issued BEFORE
        // A's poll — their HBM latency hides under the h-hop wait. The "memory"
        // clobbers on A's asm pin them here (no hoist/sink across).
        float4 xr0[4], xr1[4];
        {
            const float* xb = x + (size_t)((t + 1 < T_) ? t + 1 : t) * (B_ * D_)
                              + c16 * D_;
            #pragma unroll
            for (int i = 0; i < 4; ++i) {
                const float* xp = xb + (wv + 8 * i) * 32 + q * 8;
                xr0[i] = *(const float4*)xp;
                xr1[i] = *(const float4*)(xp + 4);
            }
        }

        // ================ A: P1 h-part (batched self-validating poll) ================
        if (t == 0) {
            #pragma unroll
            for (int i = 0; i < 4; ++i) {
                int kc = 32 + wv + i * 8;
                const float* hp = h0 + c16 * D_ + (kc - 32) * 32 + q * 8;
                bf16x8 af = pack8(*(const float4*)hp, *(const float4*)(hp + 4));
                bf16x8 w1 = *(const bf16x8*)(sm + W1F + kc * 1024 + l * 16);
                accP1 = __builtin_amdgcn_mfma_f32_16x16x32_bf16(af, w1, accP1, 0, 0, 0);
            }
        } else {
            const unsigned* hb = hxg + sR * 8192;
            const unsigned* p0 = hb + ((4 * wv +  0 + q) * 16 + c16) * 4;
            const unsigned* p1 = hb + ((4 * wv + 32 + q) * 16 + c16) * 4;
            const unsigned* p2 = hb + ((4 * wv + 64 + q) * 16 + c16) * 4;
            const unsigned* p3 = hb + ((4 * wv + 96 + q) * 16 + c16) * 4;
            u32x4 h0v, h1v, h2v, h3v;
            ld4(p0, p1, p2, p3, h0v, h1v, h2v, h3v);
            // batched retry: one RT per round refreshes ALL stale granules
            while (bad4(h0v) || bad4(h1v) || bad4(h2v) || bad4(h3v))
                ld4(p0, p1, p2, p3, h0v, h1v, h2v, h3v);
            #pragma unroll
            for (int i = 0; i < 4; ++i) {
                u32x4 hv = (i == 0) ? h0v : (i == 1) ? h1v : (i == 2) ? h2v : h3v;
                bf16x8 w1 = *(const bf16x8*)(sm + W1F + (32 + wv + 8 * i) * 1024 + l * 16);
                accP1 = __builtin_amdgcn_mfma_f32_16x16x32_bf16(fragu(hv), w1, accP1, 0, 0, 0);
            }
        }

        // ================ B: reduce + tanh + EARLY publish hidden(t) ================
        #pragma unroll
        for (int i = 0; i < 4; ++i)
            REDF[wv * REDS + (q * 4 + i) * 16 + c16] = accP1[i];
        if (c16 < 8) {
            #pragma unroll
            for (int i = 0; i < 4; ++i)
                GREDF[wv * GRS + (q * 4 + i) * 8 + c16] = accG[i];
        }
        __syncthreads();   // sync1: all waves past A => slot sP's readers done grid-wide
        if (wv < 4) {            // distributed finalize + IMMEDIATE publish
            const int e = wv * 64 + l;
            float s = 0;
            #pragma unroll
            for (int w = 0; w < 8; ++w) s += REDF[w * REDS + e];
            float tv = tanhf(s);
            float nb = __shfl_down(tv, 1, 64);
            if (!(l & 1))       // slot sW-block-g poisoned @t-1B, drained @t-1D => safe
                stcg_u(hidg + sW * 16384 + g * 128 + (e >> 1), packbf(tv, nb));
        } else if (wv == 4 || wv == 5) {   // gate-x partial -> GPF (read in E)
            const int gt = (wv - 4) * 64 + l;
            float s = 0;
            #pragma unroll
            for (int w = 0; w < 8; ++w) s += GREDF[w * GRS + gt];
            GPF[gt] = s;
        } else if (wv == 6) {    // poison hidg slot sP — NO drain (D's ld8 vmcnt(0)
            unsigned* z1 = hidg + sP * 16384 + g * 128 + l;   //  drains before sync3)
            stcg_u(z1, POIS); stcg_u(z1 + 64, POIS);
        } else {                 // wv == 7: poison hxg slot sP — no drain (same proof)
            stcg_u(hxg + sP * 8192 + g * 64 + l, POIS);
        }
        __syncthreads();   // sync2: REDF free for D; GPF ready for E

        // ================ C: x-work for t+1 — pure pack+MFMA (loads hoisted) ========
        f32x4 accP1n = {0.f, 0.f, 0.f, 0.f}, accGn = {0.f, 0.f, 0.f, 0.f};
        if (t + 1 < T_) {
            #pragma unroll
            for (int i = 0; i < 4; ++i) {
                int kc = wv + i * 8;
                bf16x8 af = pack8(xr0[i], xr1[i]);
                bf16x8 w1 = *(const bf16x8*)(sm + W1F + kc * 1024 + l * 16);
                accP1n = __builtin_amdgcn_mfma_f32_16x16x32_bf16(af, w1, accP1n, 0, 0, 0);
                const char* ga = (c16 < 8) ? (sm + WGXF + kc * 512 + q * 128 + c16 * 16) : gz;
                bf16x8 wg = *(const bf16x8*)ga;
                accGn = __builtin_amdgcn_mfma_f32_16x16x32_bf16(af, wg, accGn, 0, 0, 0);
            }
        }

        // ================ D: P2 — batched loads + batched retry ================
        {
            const unsigned* hb2 = hidg + sW * 16384;
            const unsigned* q0 = hb2 + ((2 * wv +   0 + (q >> 1)) * 16 + c16) * 8 + (q & 1) * 4;
            const unsigned* q1 = hb2 + ((2 * wv +  16 + (q >> 1)) * 16 + c16) * 8 + (q & 1) * 4;
            const unsigned* q2 = hb2 + ((2 * wv +  32 + (q >> 1)) * 16 + c16) * 8 + (q & 1) * 4;
            const unsigned* q3 = hb2 + ((2 * wv +  48 + (q >> 1)) * 16 + c16) * 8 + (q & 1) * 4;
            const unsigned* q4 = hb2 + ((2 * wv +  64 + (q >> 1)) * 16 + c16) * 8 + (q & 1) * 4;
            const unsigned* q5 = hb2 + ((2 * wv +  80 + (q >> 1)) * 16 + c16) * 8 + (q & 1) * 4;
            const unsigned* q6 = hb2 + ((2 * wv +  96 + (q >> 1)) * 16 + c16) * 8 + (q & 1) * 4;
            const unsigned* q7 = hb2 + ((2 * wv + 112 + (q >> 1)) * 16 + c16) * 8 + (q & 1) * 4;
            u32x4 u0, u1, u2, u3, u4, u5, u6, u7;
            ld8(q0, q1, q2, q3, q4, q5, q6, q7, u0, u1, u2, u3, u4, u5, u6, u7);
            while (bad4(u0) || bad4(u1) || bad4(u2) || bad4(u3) ||
                   bad4(u4) || bad4(u5) || bad4(u6) || bad4(u7))
                ld8(q0, q1, q2, q3, q4, q5, q6, q7, u0, u1, u2, u3, u4, u5, u6, u7);
            f32x4 acc2 = {0.f, 0.f, 0.f, 0.f};
            #pragma unroll
            for (int i = 0; i < 8; ++i) {
                u32x4 uv = (i == 0) ? u0 : (i == 1) ? u1 : (i == 2) ? u2 : (i == 3) ? u3
                         : (i == 4) ? u4 : (i == 5) ? u5 : (i == 6) ? u6 : u7;
                bf16x8 w2 = *(const bf16x8*)(sm + W2CF + (wv + 8 * i) * 1024 + l * 16);
                acc2 = __builtin_amdgcn_mfma_f32_16x16x32_bf16(fragu(uv), w2, acc2, 0, 0, 0);
            }
            #pragma unroll
            for (int i = 0; i < 4; ++i)
                REDF[wv * REDS + (q * 4 + i) * 16 + c16] = acc2[i];
        }

        // ================ E: finalize out, EARLY publish h(t); no sync4 ============
        __syncthreads();   // sync3: D's REDF writes visible
        if (wv < 2) {      // 1 output per lane across waves 0-1 (e = b*8 + r)
            const int e = wv * 64 + l, b = e >> 3, r = e & 7;
            float hn = 0, uv = 0;
            #pragma unroll
            for (int w = 0; w < 8; ++w) {
                hn += REDF[w * REDS + b * 16 + r];
                uv += REDF[w * REDS + b * 16 + 8 + r];
            }
            uv += GPF[e] + BIF[r];
            float sig = 1.0f / (1.0f + __expf(-uv));
            float ov = hn * (uv * sig);
            float nb = __shfl_down(ov, 1, 64);
            if (!(l & 1))       // publish FIRST (consumers wait on this store)
                stcg_u(hxg + sW * 8192 + (g * 16 + b) * 4 + ((e & 7) >> 1),
                       packbf(ov, nb));
            out[(size_t)t * (B_ * D_) + b * D_ + g * 8 + r] = ov;   // plain cached
        }
        // no sync4: E's REDF/GPF reads are ordered against B(t+1) writes by sync1(t+1);
        // A(t+1) pollers self-validate against in-flight publishes.

        // rotate slots: next step writes sP, reads sW, poisons sR(old)
        int tmp = sR; sR = sW; sW = sP; sP = tmp;
        accP1 = accP1n; accG = accGn;
    }
}

extern "C" void kernel_launch(void* const* d_in, const int* in_sizes, int n_in,
                              void* d_out, int out_size, void* d_ws, size_t ws_size,
                              hipStream_t stream) {
    const float* x    = (const float*)d_in[0];
    const float* h0   = (const float*)d_in[1];
    const float* W1   = (const float*)d_in[2];
    const float* W2   = (const float*)d_in[3];
    const float* Wgx  = (const float*)d_in[4];
    const float* Wgh  = (const float*)d_in[5];
    const float* bias = (const float*)d_in[6];
    float* out = (float*)d_out;

    unsigned* hidg = (unsigned*)d_ws;          // 3 slots x 64KB = 192 KB
    unsigned* hxg  = hidg + 3 * 16384;         // 3 slots x 32KB = 96 KB

    // All ring slots start as POISON (0xFF bytes); runs every launch/replay.
    hipMemsetAsync(d_ws, 0xFF, 294912, stream);

    hipFuncSetAttribute((const void*)elman15,
                        hipFuncAttributeMaxDynamicSharedMemorySize, LDS_BYTES);

    void* args[] = {(void*)&x, (void*)&h0, (void*)&W1, (void*)&W2,
                    (void*)&Wgx, (void*)&Wgh, (void*)&bias, (void*)&out,
                    (void*)&hxg, (void*)&hidg};
    hipLaunchCooperativeKernel((const void*)elman15,
                               dim3(NWG), dim3(TPB), args,
                               (unsigned)LDS_BYTES, stream);
}